// Round 7
// baseline (60.420 us; speedup 1.0000x reference)
//
#include <hip/hip_runtime.h>

#define NDIM 1024
#define BATCH 16

typedef float fvec4 __attribute__((ext_vector_type(4)));

// Raw (pre-shuffle) patch: 3 vec4 rows + one lane-selected halo scalar per row
// (lane tx==0 holds the left halo, lane tx==15 holds the right halo).
struct Patch {
    fvec4 m0, m1, m2;
    float h0, h1, h2;
};

// Fused spatially-varying 3x3 filter:
//   K[p,i,j] = bias[p] + sum_{m,n} w[p,0,m,n] * image_pad[i+m, j+n]
//   y[b,i,j] = sum_{k,l} K[3k+l,i,j] * x_pad[b, i+k, j+l]
// One block owns a 64x16 pixel tile for ALL 16 batches (K built once per
// pixel; grid = 1024 blocks = 4 resident blocks/CU). 3-deep rotating prefetch.
// amdgpu_waves_per_eu(4,4) pins occupancy to 4 waves/EU: R5/R6 showed the
// allocator targets 8 waves/EU (64 VGPR) by default and SPILLS the ~110 live
// floats (+35MB WRITE_SIZE of scratch) instead of using the 128-VGPR budget
// that __launch_bounds__(256,4) merely *permits*.
__global__ __launch_bounds__(256)
__attribute__((amdgpu_waves_per_eu(4, 4)))
void smallsm_fused(
    const float* __restrict__ image,
    const float* __restrict__ x,
    const float* __restrict__ w,
    const float* __restrict__ bias,
    float* __restrict__ out)
{
    const int N = NDIM;
    const int tx = threadIdx.x & 15;   // 16 threads in j (x4 pixels = 64 cols)
    const int ty = threadIdx.x >> 4;   // 16 threads in i
    const int j0 = (blockIdx.x * 16 + tx) * 4;
    const int i  = blockIdx.y * 16 + ty;

    const bool is_l = (tx == 0);
    const bool is_r = (tx == 15);
    const bool hp   = (is_l && j0 > 0) || (is_r && j0 + 4 < N);
    const int  hoff = is_r ? (j0 + 4) : (j0 - 1);   // lane-selected halo column

    // Issue loads for one 3-row patch. No waits consumed here.
    auto issue_patch = [&](const float* __restrict__ base, Patch& p) {
#pragma unroll
        for (int r = 0; r < 3; ++r) {
            const int row = i - 1 + r;
            const bool rv = (row >= 0) && (row < N);
            const float* rp = base + (size_t)row * N;
            fvec4 mv = {0.f, 0.f, 0.f, 0.f};
            if (rv) mv = *reinterpret_cast<const fvec4*>(rp + j0);
            float hv = 0.f;
            if (rv && hp) hv = rp[hoff];     // one masked load, lanes {0,15}/group
            if (r == 0) { p.m0 = mv; p.h0 = hv; }
            if (r == 1) { p.m1 = mv; p.h1 = hv; }
            if (r == 2) { p.m2 = mv; p.h2 = hv; }
        }
    };

    // Raw patch -> 3x6 window via neighbor-lane shuffles.
    auto finish_patch = [&](const Patch& p, float (&v)[3][6]) {
#pragma unroll
        for (int r = 0; r < 3; ++r) {
            const fvec4 m  = (r == 0) ? p.m0 : (r == 1) ? p.m1 : p.m2;
            const float hv = (r == 0) ? p.h0 : (r == 1) ? p.h1 : p.h2;
            float left  = __shfl_up(m.w, 1);    // lane tx-1's last element
            float right = __shfl_down(m.x, 1);  // lane tx+1's first element
            if (is_l) left  = hv;               // crossed 16-lane row group
            if (is_r) right = hv;
            v[r][0] = left; v[r][1] = m.x; v[r][2] = m.y;
            v[r][3] = m.z;  v[r][4] = m.w; v[r][5] = right;
        }
    };

    float K[9][4];

    auto apply_store = [&](const float (&v)[3][6], int b) {
        float a0 = 0.f, a1 = 0.f, a2 = 0.f, a3 = 0.f;
#pragma unroll
        for (int k = 0; k < 3; ++k) {
#pragma unroll
            for (int l = 0; l < 3; ++l) {
                const int p = 3 * k + l;
                a0 += K[p][0] * v[k][l + 0];
                a1 += K[p][1] * v[k][l + 1];
                a2 += K[p][2] * v[k][l + 2];
                a3 += K[p][3] * v[k][l + 3];
            }
        }
        fvec4 res; res.x = a0; res.y = a1; res.z = a2; res.w = a3;
        fvec4* dst = reinterpret_cast<fvec4*>(
            out + (size_t)b * N * N + (size_t)i * N + j0);
        __builtin_nontemporal_store(res, dst);
    };

    // --- prologue: image + 3 batches of x in flight ---
    const size_t NN = (size_t)N * N;
    Patch pim, P0, P1, P2;            // named, register-resident
    issue_patch(image, pim);
    issue_patch(x + 0 * NN, P0);
    issue_patch(x + 1 * NN, P1);
    issue_patch(x + 2 * NN, P2);

    // --- per-pixel kernels K[9][4] (waits only on image loads; the 324-FMA
    //     build runs while the 3 x-batches are still in flight) ---
    {
        float im[3][6];
        finish_patch(pim, im);
#pragma unroll
        for (int p = 0; p < 9; ++p) {
            const float bv = bias[p];
            float a0 = bv, a1 = bv, a2 = bv, a3 = bv;
#pragma unroll
            for (int m = 0; m < 3; ++m) {
#pragma unroll
                for (int n = 0; n < 3; ++n) {
                    const float wv = w[p * 9 + m * 3 + n];
                    a0 += wv * im[m][0 + n];
                    a1 += wv * im[m][1 + n];
                    a2 += wv * im[m][2 + n];
                    a3 += wv * im[m][3 + n];
                }
            }
            K[p][0] = a0; K[p][1] = a1; K[p][2] = a2; K[p][3] = a3;
        }
    }

    // --- 16-batch pipeline: consume BUF (vmcnt-waits batch T only),
    //     refill BUF with batch T+3, FMAs+store while those loads fly. ---
#define STEP(T, BUF) do {                                        \
        float v[3][6];                                           \
        finish_patch(BUF, v);                                    \
        if ((T) + 3 < BATCH)                                     \
            issue_patch(x + (size_t)((T) + 3) * NN, BUF);        \
        apply_store(v, (T));                                     \
    } while (0)

    STEP(0,  P0); STEP(1,  P1); STEP(2,  P2);
    STEP(3,  P0); STEP(4,  P1); STEP(5,  P2);
    STEP(6,  P0); STEP(7,  P1); STEP(8,  P2);
    STEP(9,  P0); STEP(10, P1); STEP(11, P2);
    STEP(12, P0); STEP(13, P1); STEP(14, P2);
    STEP(15, P0);
#undef STEP
}

extern "C" void kernel_launch(void* const* d_in, const int* in_sizes, int n_in,
                              void* d_out, int out_size, void* d_ws, size_t ws_size,
                              hipStream_t stream) {
    const float* image = (const float*)d_in[0];
    const float* x     = (const float*)d_in[1];
    const float* w     = (const float*)d_in[2];
    const float* bias  = (const float*)d_in[3];
    float* out = (float*)d_out;

    dim3 grid(NDIM / 64, NDIM / 16, 1);
    dim3 block(256);
    hipLaunchKernelGGL(smallsm_fused, grid, block, 0, stream,
                       image, x, w, bias, out);
}

// Round 8
// 50.579 us; speedup vs baseline: 1.1946x; 1.1946x over previous
//
#include <hip/hip_runtime.h>

#define NDIM 1024
#define BATCH 16

typedef float fvec4 __attribute__((ext_vector_type(4)));

// Raw (pre-shuffle) patch: 3 vec4 rows + one lane-selected halo scalar per row
// (lane tx==0 holds the left halo, lane tx==15 holds the right halo).
struct Patch {
    fvec4 m0, m1, m2;
    float h0, h1, h2;
};

// Fused spatially-varying 3x3 filter:
//   K[p,i,j] = bias[p] + sum_{m,n} w[p,0,m,n] * image_pad[i+m, j+n]
//   y[b,i,j] = sum_{k,l} K[3k+l,i,j] * x_pad[b, i+k, j+l]
// One block owns a 64x16 tile for ALL 16 batches; K built ONCE per pixel and
// parked in LDS (Klds[9][256], 36KB) — R5-R7 proved K(36 regs) + pipeline
// patches cannot fit the 64-VGPR allocation the compiler insists on, and it
// spills (+35MB WRITE of scratch). Each thread only touches Klds[*][tid]
// (private slot -> no barrier; same-thread LDS RAW ordered by lgkmcnt).
// 3-deep rotating prefetch with named buffers; halos via lane shuffles.
__global__ __launch_bounds__(256) void smallsm_fused(
    const float* __restrict__ image,
    const float* __restrict__ x,
    const float* __restrict__ w,
    const float* __restrict__ bias,
    float* __restrict__ out)
{
    __shared__ fvec4 Klds[9][256];   // [tap][thread] -> 36864 B

    const int N = NDIM;
    const int tid = threadIdx.x;
    const int tx = tid & 15;          // 16 threads in j (x4 pixels = 64 cols)
    const int ty = tid >> 4;          // 16 threads in i
    const int j0 = (blockIdx.x * 16 + tx) * 4;
    const int i  = blockIdx.y * 16 + ty;

    const bool is_l = (tx == 0);
    const bool is_r = (tx == 15);
    const bool hp   = (is_l && j0 > 0) || (is_r && j0 + 4 < N);
    const int  hoff = is_r ? (j0 + 4) : (j0 - 1);   // lane-selected halo column

    // Issue loads for one 3-row patch. No waits consumed here.
    auto issue_patch = [&](const float* __restrict__ base, Patch& p) {
#pragma unroll
        for (int r = 0; r < 3; ++r) {
            const int row = i - 1 + r;
            const bool rv = (row >= 0) && (row < N);
            const float* rp = base + (size_t)row * N;
            fvec4 mv = {0.f, 0.f, 0.f, 0.f};
            if (rv) mv = *reinterpret_cast<const fvec4*>(rp + j0);
            float hv = 0.f;
            if (rv && hp) hv = rp[hoff];     // one masked load, lanes {0,15}/group
            if (r == 0) { p.m0 = mv; p.h0 = hv; }
            if (r == 1) { p.m1 = mv; p.h1 = hv; }
            if (r == 2) { p.m2 = mv; p.h2 = hv; }
        }
    };

    // Raw patch -> 3x6 window via neighbor-lane shuffles.
    auto finish_patch = [&](const Patch& p, float (&v)[3][6]) {
#pragma unroll
        for (int r = 0; r < 3; ++r) {
            const fvec4 m  = (r == 0) ? p.m0 : (r == 1) ? p.m1 : p.m2;
            const float hv = (r == 0) ? p.h0 : (r == 1) ? p.h1 : p.h2;
            float left  = __shfl_up(m.w, 1);    // lane tx-1's last element
            float right = __shfl_down(m.x, 1);  // lane tx+1's first element
            if (is_l) left  = hv;               // crossed 16-lane row group
            if (is_r) right = hv;
            v[r][0] = left; v[r][1] = m.x; v[r][2] = m.y;
            v[r][3] = m.z;  v[r][4] = m.w; v[r][5] = right;
        }
    };

    // Apply per-pixel kernels (streamed from LDS) to one window and store.
    auto apply_store = [&](const float (&v)[3][6], int b) {
        float a0 = 0.f, a1 = 0.f, a2 = 0.f, a3 = 0.f;
#pragma unroll
        for (int k = 0; k < 3; ++k) {
#pragma unroll
            for (int l = 0; l < 3; ++l) {
                const fvec4 kv = Klds[3 * k + l][tid];
                a0 += kv.x * v[k][l + 0];
                a1 += kv.y * v[k][l + 1];
                a2 += kv.z * v[k][l + 2];
                a3 += kv.w * v[k][l + 3];
            }
        }
        fvec4 res; res.x = a0; res.y = a1; res.z = a2; res.w = a3;
        fvec4* dst = reinterpret_cast<fvec4*>(
            out + (size_t)b * N * N + (size_t)i * N + j0);
        __builtin_nontemporal_store(res, dst);
    };

    // --- prologue: image + 3 batches of x in flight ---
    const size_t NN = (size_t)N * N;
    Patch pim, P0, P1, P2;            // named, register-resident
    issue_patch(image, pim);
    issue_patch(x + 0 * NN, P0);
    issue_patch(x + 1 * NN, P1);
    issue_patch(x + 2 * NN, P2);

    // --- build K (waits only on image loads; x loads still in flight),
    //     park it in LDS, K registers die here ---
    {
        float im[3][6];
        finish_patch(pim, im);
#pragma unroll
        for (int p = 0; p < 9; ++p) {
            const float bv = bias[p];
            float a0 = bv, a1 = bv, a2 = bv, a3 = bv;
#pragma unroll
            for (int m = 0; m < 3; ++m) {
#pragma unroll
                for (int n = 0; n < 3; ++n) {
                    const float wv = w[p * 9 + m * 3 + n];
                    a0 += wv * im[m][0 + n];
                    a1 += wv * im[m][1 + n];
                    a2 += wv * im[m][2 + n];
                    a3 += wv * im[m][3 + n];
                }
            }
            fvec4 kv; kv.x = a0; kv.y = a1; kv.z = a2; kv.w = a3;
            Klds[p][tid] = kv;        // private slot: no barrier needed
        }
    }

    // --- 16-batch pipeline: consume BUF (vmcnt-waits batch T only),
    //     refill BUF with batch T+3, FMAs+store while those loads fly. ---
#define STEP(T, BUF) do {                                        \
        float v[3][6];                                           \
        finish_patch(BUF, v);                                    \
        if ((T) + 3 < BATCH)                                     \
            issue_patch(x + (size_t)((T) + 3) * NN, BUF);        \
        apply_store(v, (T));                                     \
    } while (0)

    STEP(0,  P0); STEP(1,  P1); STEP(2,  P2);
    STEP(3,  P0); STEP(4,  P1); STEP(5,  P2);
    STEP(6,  P0); STEP(7,  P1); STEP(8,  P2);
    STEP(9,  P0); STEP(10, P1); STEP(11, P2);
    STEP(12, P0); STEP(13, P1); STEP(14, P2);
    STEP(15, P0);
#undef STEP
}

extern "C" void kernel_launch(void* const* d_in, const int* in_sizes, int n_in,
                              void* d_out, int out_size, void* d_ws, size_t ws_size,
                              hipStream_t stream) {
    const float* image = (const float*)d_in[0];
    const float* x     = (const float*)d_in[1];
    const float* w     = (const float*)d_in[2];
    const float* bias  = (const float*)d_in[3];
    float* out = (float*)d_out;

    dim3 grid(NDIM / 64, NDIM / 16, 1);
    dim3 block(256);
    hipLaunchKernelGGL(smallsm_fused, grid, block, 0, stream,
                       image, x, w, bias, out);
}

// Round 9
// 37.380 us; speedup vs baseline: 1.6164x; 1.3531x over previous
//
#include <hip/hip_runtime.h>
#include <stdint.h>

#define NDIM 1024
#define BATCH 16
#define BCHUNK 8           // batches per block; grid.z = 2
#define RSTRIDE 72         // floats per staged row: 64 interior + 2 halo vec4 slots
#define SROWS 18           // staged rows: i0-1 .. i0+16
#define SLOTS (SROWS * 18) // 324 vec4 slots per tile

typedef float fvec4 __attribute__((ext_vector_type(4)));

__device__ __forceinline__ float h2f(uint32_t bits16) {
    _Float16 h = __builtin_bit_cast(_Float16, (uint16_t)bits16);
    return (float)h;
}

// Fused spatially-varying 3x3 filter.
//   K[p,i,j] = bias[p] + sum w[p]*image_pad ; y[b,i,j] = sum K[p,i,j]*x_pad
// Block owns a 64x16 tile x 8 batches. x staged to LDS via global_load_lds
// (triple-buffered [18][72] f32 tiles, 15.5KB): hot loop has ZERO strided
// scalar global loads, zero shuffles, zero divergence — pure vec4 streams.
// K built once per pixel, packed fp16x2 into 18 VGPRs so total VGPR <= 64
// (the allocator's hard target; exceeding it spilled in R5-R7).
// Schedule per batch: barrier -> issue stage(b+2) -> apply(b) from LDS; the
// stage's HBM latency hides under apply + 8 staggered blocks/CU.
__global__ __launch_bounds__(256) void smallsm_fused(
    const float* __restrict__ image,
    const float* __restrict__ x,
    const float* __restrict__ w,
    const float* __restrict__ bias,
    float* __restrict__ out)
{
    __shared__ float Xlds[3][SROWS * RSTRIDE];   // 3 x 5184 B = 15552 B

    const int N   = NDIM;
    const size_t NN = (size_t)N * N;
    const int tid = threadIdx.x;
    const int tx  = tid & 15;              // 16 threads in j (x4 px = 64 cols)
    const int ty  = tid >> 4;              // 16 threads in i
    const int jB  = blockIdx.x * 64;       // block col base
    const int jT  = jB + tx * 4;           // thread col base
    const int i0  = blockIdx.y * 16;       // block row base
    const int iT  = i0 + ty;               // thread output row
    const int b0  = blockIdx.z * BCHUNK;

    const bool is_l = (tx == 0);
    const bool is_r = (tx == 15);

    // ---- staging precompute: 2 global_load_lds insts per wave ----
    // slot layout per row (18 vec4): 0..15 interior cols, 16 = [jB-4..jB-1]
    // (left halo at local float 67), 17 = [jB+64..jB+67] (right halo at 68).
    const int wid  = tid >> 6;             // wave id 0..3 (uniform per wave)
    const int lane = tid & 63;
    uint32_t soff0, soff1; bool sval0, sval1;
    {
#pragma unroll
        for (int ii = 0; ii < 2; ++ii) {
            const int S    = (wid * 2 + ii) * 64 + lane;
            const int row  = S / 18;
            const int slot = S - row * 18;
            const int colF = (slot < 16) ? slot * 4 : (slot == 16 ? -4 : 64);
            const int grow = i0 - 1 + row;
            const int gcol = jB + colF;
            const bool v = (S < SLOTS) && (grow >= 0) && (grow < N) &&
                           (gcol >= 0) && (gcol + 4 <= N);
            const uint32_t o = (uint32_t)(grow * N + gcol);
            if (ii == 0) { sval0 = v; soff0 = o; }
            else         { sval1 = v; soff1 = o; }
        }
    }

    // stage batch b into buffer `buf` (buf is a literal at each call site)
    auto stage = [&](int b, int buf) {
        const float* xb = x + (size_t)(b0 + b) * NN;
        float* lb = &Xlds[buf][0];
        if (sval0)
            __builtin_amdgcn_global_load_lds(
                (const __attribute__((address_space(1))) void*)(xb + soff0),
                (__attribute__((address_space(3))) void*)(lb + (wid * 2 + 0) * 256),
                16, 0, 0);
        if (sval1)
            __builtin_amdgcn_global_load_lds(
                (const __attribute__((address_space(1))) void*)(xb + soff1),
                (__attribute__((address_space(3))) void*)(lb + (wid * 2 + 1) * 256),
                16, 0, 0);
    };

    // ---- prologue: image loads first (K-build waits only on them),
    //      then batches 0,1 staged (stay in flight during K-build) ----
    const bool jm_ok = (jT > 0);
    const bool jp_ok = (jT + 4 < N);
    float im_m[3][4]; float im_h[3]; // vec4 rows + lane-selected halo scalar
    const int hoff = is_r ? (jT + 4) : (jT - 1);
    const bool hp  = (is_l && jm_ok) || (is_r && jp_ok);
#pragma unroll
    for (int r = 0; r < 3; ++r) {
        const int row = iT - 1 + r;
        const bool rv = (row >= 0) && (row < N);
        const float* rp = image + (size_t)row * N;
        fvec4 mv = {0.f, 0.f, 0.f, 0.f};
        if (rv) mv = *reinterpret_cast<const fvec4*>(rp + jT);
        im_h[r] = (rv && hp) ? rp[hoff] : 0.f;
        im_m[r][0] = mv.x; im_m[r][1] = mv.y; im_m[r][2] = mv.z; im_m[r][3] = mv.w;
    }
    stage(0, 0);
    stage(1, 1);

    // ---- build K (fp32 math), pack to fp16x2: Kp[18] ----
    uint32_t Kp[18];
    {
        float im[3][6];
#pragma unroll
        for (int r = 0; r < 3; ++r) {
            float left  = __shfl_up(im_m[r][3], 1);
            float right = __shfl_down(im_m[r][0], 1);
            if (is_l) left  = im_h[r];
            if (is_r) right = im_h[r];
            im[r][0] = left;       im[r][1] = im_m[r][0]; im[r][2] = im_m[r][1];
            im[r][3] = im_m[r][2]; im[r][4] = im_m[r][3]; im[r][5] = right;
        }
#pragma unroll
        for (int p = 0; p < 9; ++p) {
            const float bv = bias[p];
            float a0 = bv, a1 = bv, a2 = bv, a3 = bv;
#pragma unroll
            for (int m = 0; m < 3; ++m) {
#pragma unroll
                for (int n = 0; n < 3; ++n) {
                    const float wv = w[p * 9 + m * 3 + n];
                    a0 += wv * im[m][0 + n];
                    a1 += wv * im[m][1 + n];
                    a2 += wv * im[m][2 + n];
                    a3 += wv * im[m][3 + n];
                }
            }
            const uint16_t h0 = __builtin_bit_cast(uint16_t, (_Float16)a0);
            const uint16_t h1 = __builtin_bit_cast(uint16_t, (_Float16)a1);
            const uint16_t h2 = __builtin_bit_cast(uint16_t, (_Float16)a2);
            const uint16_t h3 = __builtin_bit_cast(uint16_t, (_Float16)a3);
            Kp[2 * p]     = (uint32_t)h0 | ((uint32_t)h1 << 16);
            Kp[2 * p + 1] = (uint32_t)h2 | ((uint32_t)h3 << 16);
        }
    }

    // ---- main loop: BAR -> issue stage(k+2) -> apply(k) from LDS ----
#pragma unroll
    for (int k = 0; k < BCHUNK; ++k) {
        __syncthreads();
        if (k + 2 < BCHUNK) stage(k + 2, (k + 2) % 3);

        const int buf = k % 3;
        float a0 = 0.f, a1 = 0.f, a2 = 0.f, a3 = 0.f;
#pragma unroll
        for (int r = 0; r < 3; ++r) {
            const float* rp = &Xlds[buf][(ty + r) * RSTRIDE];
            const bool rvv = ((unsigned)(i0 - 1 + ty + r) < (unsigned)N);
            fvec4 m = *reinterpret_cast<const fvec4*>(rp + 4 * tx);
            const float* lpq = is_l ? (rp + 67) : (rp + 4 * tx - 1);
            const float* rpq = is_r ? (rp + 68) : (rp + 4 * tx + 4);
            float lft = *lpq;
            float rgt = *rpq;
            if (is_l && jB == 0)      lft = 0.f;
            if (is_r && jB + 64 >= N) rgt = 0.f;
            if (!rvv) { m.x = 0.f; m.y = 0.f; m.z = 0.f; m.w = 0.f; lft = 0.f; rgt = 0.f; }
            const float wv[6] = { lft, m.x, m.y, m.z, m.w, rgt };
#pragma unroll
            for (int l = 0; l < 3; ++l) {
                const int p = 3 * r + l;
                const uint32_t u0 = Kp[2 * p], u1 = Kp[2 * p + 1];
                a0 += h2f(u0 & 0xffffu) * wv[l + 0];
                a1 += h2f(u0 >> 16)     * wv[l + 1];
                a2 += h2f(u1 & 0xffffu) * wv[l + 2];
                a3 += h2f(u1 >> 16)     * wv[l + 3];
            }
        }
        fvec4 res; res.x = a0; res.y = a1; res.z = a2; res.w = a3;
        fvec4* dst = reinterpret_cast<fvec4*>(
            out + (size_t)(b0 + k) * NN + (size_t)iT * N + jT);
        __builtin_nontemporal_store(res, dst);
    }
}

extern "C" void kernel_launch(void* const* d_in, const int* in_sizes, int n_in,
                              void* d_out, int out_size, void* d_ws, size_t ws_size,
                              hipStream_t stream) {
    const float* image = (const float*)d_in[0];
    const float* x     = (const float*)d_in[1];
    const float* w     = (const float*)d_in[2];
    const float* bias  = (const float*)d_in[3];
    float* outp = (float*)d_out;

    dim3 grid(NDIM / 64, NDIM / 16, BATCH / BCHUNK);
    dim3 block(256);
    hipLaunchKernelGGL(smallsm_fused, grid, block, 0, stream,
                       image, x, w, bias, outp);
}

// Round 10
// 35.919 us; speedup vs baseline: 1.6821x; 1.0407x over previous
//
#include <hip/hip_runtime.h>
#include <stdint.h>

#define NDIM 1024
#define BATCH 16

typedef float fvec4 __attribute__((ext_vector_type(4)));

__device__ __forceinline__ float h2f(uint32_t bits16) {
    _Float16 h = __builtin_bit_cast(_Float16, (uint16_t)bits16);
    return (float)h;
}

// Fused spatially-varying 3x3 filter, fully barrier-free.
// Each WAVE owns 4 output rows x 64 cols x all 16 batches, staging its own
// private 6-row x 72-float LDS tile via global_load_lds (triple-buffered).
// No __syncthreads anywhere: R9 showed the per-batch barrier's implicit
// s_waitcnt vmcnt(0) drains the prefetch every iteration (3.55 TB/s vs the
// 6.8 TB/s the same chip's fillBuffer sustains). Ordering is per-wave counted
// vmcnt (steady state vmcnt(4): next stage's 2 loads + 2 output stores stay
// in flight) + sched_barrier(0) pins so the static counts are exact.
// K built once per pixel, fp16x2-packed into 18 VGPRs (R9: absmax 0.125).
__global__ __launch_bounds__(256) void smallsm_fused(
    const float* __restrict__ image,
    const float* __restrict__ x,
    const float* __restrict__ w,
    const float* __restrict__ bias,
    float* __restrict__ out)
{
    __shared__ float Xlds[4][3][512];   // [wave][buf][6*72 used + pad] = 24576 B

    const int N = NDIM;
    const size_t NN = (size_t)N * N;
    const int tid  = threadIdx.x;
    const int wid  = tid >> 6;            // wave 0..3
    const int lane = tid & 63;
    const int tx   = lane & 15;           // 16 lanes in j (x4 px = 64 cols)
    const int g    = lane >> 4;           // row group 0..3 within wave
    const int jB   = blockIdx.x * 64;
    const int jT   = jB + tx * 4;
    const int iW   = blockIdx.y * 16 + wid * 4;   // wave's first output row
    const int iT   = iW + g;

    const bool is_l = (tx == 0);
    const bool is_r = (tx == 15);

    // ---- staging source offsets: 2 global_load_lds per stage ----
    // per-row layout (18 vec4 slots = 72 floats): 0..15 interior cols,
    // 16 -> [jB-4..jB-1] (left halo at float 67), 17 -> [jB+64..67] (float 68).
    // 6 rows x 18 = 108 slots; 2 loads x 64 lanes = 128 (20 dead, predicated).
    uint32_t soff0, soff1; bool sv0, sv1;
#pragma unroll
    for (int ii = 0; ii < 2; ++ii) {
        const int S    = ii * 64 + lane;
        const int row  = S / 18;
        const int slot = S - row * 18;
        const int colF = (slot < 16) ? slot * 4 : (slot == 16 ? -4 : 64);
        const int grow = iW - 1 + row;
        const int gcol = jB + colF;
        const bool v = (S < 108) && (grow >= 0) && (grow < N) &&
                       (gcol >= 0) && (gcol + 4 <= N);
        const uint32_t o = (uint32_t)(grow * N + gcol);
        if (ii == 0) { sv0 = v; soff0 = o; } else { sv1 = v; soff1 = o; }
    }
    // sv0/sv1 are never all-false across a wave (interior slots of rows 1..4
    // are always valid), so each stage issues exactly 2 wave-level VMEM ops
    // and the static vmcnt bookkeeping below is exact.

    auto stage = [&](int b, int buf) {
        const float* xb = x + (size_t)b * NN;
        float* lb = &Xlds[wid][buf][0];
        if (sv0)
            __builtin_amdgcn_global_load_lds(
                (const __attribute__((address_space(1))) void*)(xb + soff0),
                (__attribute__((address_space(3))) void*)(lb), 16, 0, 0);
        if (sv1)
            __builtin_amdgcn_global_load_lds(
                (const __attribute__((address_space(1))) void*)(xb + soff1),
                (__attribute__((address_space(3))) void*)(lb + 256), 16, 0, 0);
    };

    // ---- prologue: image loads (K-build input), then stages 0,1 ----
    const bool hpred = (is_l && jT > 0) || (is_r && jT + 4 < N);
    const int  hoff  = is_r ? (jT + 4) : (jT - 1);
    float im_m[3][4], im_h[3];
#pragma unroll
    for (int r = 0; r < 3; ++r) {
        const int row = iT - 1 + r;
        const bool rv = (row >= 0) && (row < N);
        const float* rp = image + (size_t)row * N;
        fvec4 mv = {0.f, 0.f, 0.f, 0.f};
        if (rv) mv = *reinterpret_cast<const fvec4*>(rp + jT);
        im_h[r] = (rv && hpred) ? rp[hoff] : 0.f;
        im_m[r][0] = mv.x; im_m[r][1] = mv.y; im_m[r][2] = mv.z; im_m[r][3] = mv.w;
    }
    __builtin_amdgcn_sched_barrier(0);
    stage(0, 0);
    stage(1, 1);
    __builtin_amdgcn_sched_barrier(0);

    // ---- build K (fp32), pack fp16x2 -> Kp[18] (runs under stage latency) ----
    uint32_t Kp[18];
    {
        float im[3][6];
#pragma unroll
        for (int r = 0; r < 3; ++r) {
            float left  = __shfl_up(im_m[r][3], 1);
            float right = __shfl_down(im_m[r][0], 1);
            if (is_l) left  = im_h[r];
            if (is_r) right = im_h[r];
            im[r][0] = left;       im[r][1] = im_m[r][0]; im[r][2] = im_m[r][1];
            im[r][3] = im_m[r][2]; im[r][4] = im_m[r][3]; im[r][5] = right;
        }
#pragma unroll
        for (int p = 0; p < 9; ++p) {
            const float bv = bias[p];
            float a0 = bv, a1 = bv, a2 = bv, a3 = bv;
#pragma unroll
            for (int m = 0; m < 3; ++m) {
#pragma unroll
                for (int n = 0; n < 3; ++n) {
                    const float wv = w[p * 9 + m * 3 + n];
                    a0 += wv * im[m][0 + n];
                    a1 += wv * im[m][1 + n];
                    a2 += wv * im[m][2 + n];
                    a3 += wv * im[m][3 + n];
                }
            }
            const uint16_t q0 = __builtin_bit_cast(uint16_t, (_Float16)a0);
            const uint16_t q1 = __builtin_bit_cast(uint16_t, (_Float16)a1);
            const uint16_t q2 = __builtin_bit_cast(uint16_t, (_Float16)a2);
            const uint16_t q3 = __builtin_bit_cast(uint16_t, (_Float16)a3);
            Kp[2 * p]     = (uint32_t)q0 | ((uint32_t)q1 << 16);
            Kp[2 * p + 1] = (uint32_t)q2 | ((uint32_t)q3 << 16);
        }
    }

    // ---- apply batch k from buffer buf (literal), store result ----
    auto apply = [&](int k, int buf) {
        const float* base = &Xlds[wid][buf][0];
        float a0 = 0.f, a1 = 0.f, a2 = 0.f, a3 = 0.f;
#pragma unroll
        for (int r = 0; r < 3; ++r) {
            const float* rp = base + (g + r) * 72;
            const bool rv = ((unsigned)(iT - 1 + r) < (unsigned)N);
            fvec4 m = *reinterpret_cast<const fvec4*>(rp + 4 * tx);
            float lft = is_l ? rp[67] : rp[4 * tx - 1];
            float rgt = is_r ? rp[68] : rp[4 * tx + 4];
            if (is_l && jB == 0)      lft = 0.f;
            if (is_r && jB + 64 >= N) rgt = 0.f;
            if (!rv) { m.x = 0.f; m.y = 0.f; m.z = 0.f; m.w = 0.f; lft = 0.f; rgt = 0.f; }
            const float wv[6] = { lft, m.x, m.y, m.z, m.w, rgt };
#pragma unroll
            for (int l = 0; l < 3; ++l) {
                const int p = 3 * r + l;
                const uint32_t u0 = Kp[2 * p], u1 = Kp[2 * p + 1];
                a0 += h2f(u0 & 0xffffu) * wv[l + 0];
                a1 += h2f(u0 >> 16)     * wv[l + 1];
                a2 += h2f(u1 & 0xffffu) * wv[l + 2];
                a3 += h2f(u1 >> 16)     * wv[l + 3];
            }
        }
        fvec4 res; res.x = a0; res.y = a1; res.z = a2; res.w = a3;
        fvec4* dst = reinterpret_cast<fvec4*>(
            out + (size_t)k * NN + (size_t)iT * N + jT);
        __builtin_nontemporal_store(res, dst);
    };

    // ---- barrier-free 16-batch pipeline.
    // vmcnt bookkeeping (order pinned by sched_barrier): iter body issues
    // stage(k+2) [2 loads] then apply/store(k) [1 store]. At iter k's wait,
    // ops newer than stage(k)'s last load = {st(k-2), s(k+1)x2, st(k-1)} = 4.
#define WAITV(NIMM) do {                                              \
        asm volatile("s_waitcnt vmcnt(" #NIMM ")" ::: "memory");      \
        __builtin_amdgcn_sched_barrier(0);                            \
    } while (0)
#define STEP(K_, BUFR, BUFW, NIMM) do {                               \
        WAITV(NIMM);                                                  \
        if ((K_) + 2 < BATCH) stage((K_) + 2, BUFW);                  \
        __builtin_amdgcn_sched_barrier(0);                            \
        apply((K_), BUFR);                                            \
    } while (0)

    STEP(0,  0, 2, 2);
    STEP(1,  1, 0, 3);
    STEP(2,  2, 1, 4);
    STEP(3,  0, 2, 4);
    STEP(4,  1, 0, 4);
    STEP(5,  2, 1, 4);
    STEP(6,  0, 2, 4);
    STEP(7,  1, 0, 4);
    STEP(8,  2, 1, 4);
    STEP(9,  0, 2, 4);
    STEP(10, 1, 0, 4);
    STEP(11, 2, 1, 4);
    STEP(12, 0, 2, 4);
    STEP(13, 1, 0, 4);
    STEP(14, 2, 0, 4);   // no stage(16); BUFW unused
    STEP(15, 0, 0, 2);   // no stage(17); only st13,st14 newer than s15
#undef STEP
#undef WAITV
}

extern "C" void kernel_launch(void* const* d_in, const int* in_sizes, int n_in,
                              void* d_out, int out_size, void* d_ws, size_t ws_size,
                              hipStream_t stream) {
    const float* image = (const float*)d_in[0];
    const float* x     = (const float*)d_in[1];
    const float* w     = (const float*)d_in[2];
    const float* bias  = (const float*)d_in[3];
    float* outp = (float*)d_out;

    dim3 grid(NDIM / 64, NDIM / 16, 1);
    dim3 block(256);
    hipLaunchKernelGGL(smallsm_fused, grid, block, 0, stream,
                       image, x, w, bias, outp);
}